// Round 3
// baseline (318.870 us; speedup 1.0000x reference)
//
#include <hip/hip_runtime.h>

#define NCLS 19
#define HWSZ (512*1024)
#define NB   8
#define CHUNK 2048            // pixels per block
#define TPX   256             // pixels per staged tile
#define NT    (CHUNK/TPX)     // 8 tiles per chunk
#define EPSM  1e-6f
#define EPSPD 1e-6f

// ws: sums[n][t][row 0..19][col 0..31] f32; row=channel (t=0 row19 = counts), col=class
#define ROWP 20
#define COLP 32
#define SUMS_ELEMS (NB*2*ROWP*COLP)
#define F4T  (NCLS*TPX/4)     // 1216 float4 per tensor-tile
#define NLD  5                // staging float4 loads per thread per tensor

typedef short bf16x8 __attribute__((ext_vector_type(8)));
typedef float f32x16 __attribute__((ext_vector_type(16)));

__device__ __forceinline__ short bfh(float v) {
    return (short)(__builtin_bit_cast(unsigned, v) >> 16);
}
__device__ __forceinline__ short bfl(float v) {
    unsigned u = __builtin_bit_cast(unsigned, v);
    float lf = v - __builtin_bit_cast(float, u & 0xFFFF0000u);
    return (short)(__builtin_bit_cast(unsigned, lf) >> 16);
}

__global__ __launch_bounds__(256, 3) void icl_sums(
    const float* __restrict__ S, const float* __restrict__ T,
    const int* __restrict__ gt, float* __restrict__ sums)
{
    __shared__ float Sb[NCLS * TPX];          // XOR-swizzled 16B granules
    __shared__ float Tb[NCLS * TPX];
    __shared__ int   lab[CHUNK];
    __shared__ float red[2][ROWP][COLP];      // stays zero during compute (zero-source for r>=19)

    const int tid = threadIdx.x;
    const int n   = blockIdx.y;
    const long chunk0 = (long)blockIdx.x * CHUNK;

    for (int i = tid; i < 2 * ROWP * COLP; i += 256) ((float*)red)[i] = 0.f;

    // labels for the whole chunk -> regs (coalesced), written to LDS in phase 0
    const int4* gp = (const int4*)(gt + (long)n * HWSZ + chunk0);
    const int4 lr0 = gp[tid];
    const int4 lr1 = gp[tid + 256];

    const int wave = tid >> 6;
    const int lane = tid & 63;
    const int r    = lane & 31;     // A-row (channel) / B-col (class)
    const int kg   = lane >> 5;     // 8-pixel half of the 16-pixel K-step
    const bool isT = wave >= 2;     // waves 0,1 -> S ; 2,3 -> T
    const int  ph  = wave & 1;      // pixel half of the 256-px tile

    float4 sreg[NLD], treg[NLD];

    f32x16 acc = {0,0,0,0,0,0,0,0,0,0,0,0,0,0,0,0};
    const bf16x8 ones = {0x3F80,0x3F80,0x3F80,0x3F80,0x3F80,0x3F80,0x3F80,0x3F80};

    const float* xb = isT ? Tb : Sb;
    const float* zb = (const float*)red;      // all-zero source for r >= NCLS

    auto load_tile = [&](int t) {
#pragma unroll
        for (int j = 0; j < NLD; ++j) {
            int f = tid + j * 256;
            f = (f < F4T) ? f : (F4T - 1);
            const int row = f >> 6;           // 64 float4 granules per 256-px row
            const int g   = f & 63;
            const long off = ((long)(n * NCLS + row)) * HWSZ + chunk0 + (long)t * TPX + g * 4;
            sreg[j] = *(const float4*)(S + off);
            treg[j] = *(const float4*)(T + off);
        }
    };

    auto write_tile = [&]() {
#pragma unroll
        for (int j = 0; j < NLD; ++j) {
            const int f = tid + j * 256;
            if (f < F4T) {
                const int row = f >> 6;
                const int gw  = (f & 63) ^ (row & 7);   // both-sides XOR swizzle
                ((float4*)Sb)[row * 64 + gw] = sreg[j];
                ((float4*)Tb)[row * 64 + gw] = treg[j];
            }
        }
    };

    load_tile(0);

    for (int t = 0; t < NT; ++t) {
        __syncthreads();                       // LDS free (prev tile's compute done)
        if (t == 0) {
            ((int4*)lab)[tid]       = lr0;
            ((int4*)lab)[tid + 256] = lr1;
        }
        write_tile();                          // vmcnt wait lands here (loads issued last iter)
        __syncthreads();
        if (t + 1 < NT) load_tile(t + 1);      // issue early; hides under compute below

#pragma unroll
        for (int st = 0; st < 8; ++st) {
            const int px = ph * 128 + st * 16 + kg * 8;   // within tile

            // B fragment: one-hot of labels (exact in bf16); broadcast LDS reads
            const int4 l0 = *(const int4*)&lab[t * TPX + px];
            const int4 l1 = *(const int4*)&lab[t * TPX + px + 4];
            bf16x8 B;
            B[0] = (l0.x == r) ? (short)0x3F80 : (short)0;
            B[1] = (l0.y == r) ? (short)0x3F80 : (short)0;
            B[2] = (l0.z == r) ? (short)0x3F80 : (short)0;
            B[3] = (l0.w == r) ? (short)0x3F80 : (short)0;
            B[4] = (l1.x == r) ? (short)0x3F80 : (short)0;
            B[5] = (l1.y == r) ? (short)0x3F80 : (short)0;
            B[6] = (l1.z == r) ? (short)0x3F80 : (short)0;
            B[7] = (l1.w == r) ? (short)0x3F80 : (short)0;

            // A fragment from LDS (swizzled); lanes r>=19 read zeros from red[]
            const int go  = px >> 2;
            const int gr0 = go ^ (r & 7);
            const int gr1 = (go + 1) ^ (r & 7);
            const float4* f4 = (const float4*)((r < NCLS) ? (xb + r * TPX) : zb);
            const float4 d0 = f4[gr0];
            const float4 d1 = f4[gr1];

            bf16x8 hi, lo;
            hi[0]=bfh(d0.x); lo[0]=bfl(d0.x);  hi[1]=bfh(d0.y); lo[1]=bfl(d0.y);
            hi[2]=bfh(d0.z); lo[2]=bfl(d0.z);  hi[3]=bfh(d0.w); lo[3]=bfl(d0.w);
            hi[4]=bfh(d1.x); lo[4]=bfl(d1.x);  hi[5]=bfh(d1.y); lo[5]=bfl(d1.y);
            hi[6]=bfh(d1.z); lo[6]=bfl(d1.z);  hi[7]=bfh(d1.w); lo[7]=bfl(d1.w);

            if (r == NCLS && !isT) hi = ones;  // count row (S-waves only); lo stays 0

            acc = __builtin_amdgcn_mfma_f32_32x32x16_bf16(hi, B, acc, 0, 0, 0);
            acc = __builtin_amdgcn_mfma_f32_32x32x16_bf16(lo, B, acc, 0, 0, 0);
        }
    }

    // C/D layout: col = lane&31, row = (e&3) + 8*(e>>2) + 4*(lane>>5)
#pragma unroll
    for (int e = 0; e < 16; ++e) {
        const int row = (e & 3) + 8 * (e >> 2) + 4 * kg;
        if (row < ROWP) atomicAdd(&red[isT ? 1 : 0][row][r], acc[e]);
    }
    __syncthreads();

    float* gs = sums + (long)n * 2 * ROWP * COLP;
    for (int i = tid; i < 2 * ROWP * COLP; i += 256) {
        if ((i & 31) < NCLS) atomicAdd(&gs[i], ((const float*)red)[i]);
    }
}

__global__ __launch_bounds__(256) void icl_final(
    const float* __restrict__ sums, float* __restrict__ out)
{
    __shared__ float v[NB][2][NCLS][NCLS];   // [n][t][k][c]
    __shared__ float red2[256];
    const int tid = threadIdx.x;

    for (int i = tid; i < NB * 2 * NCLS * NCLS; i += 256) {
        const int c = i % NCLS;
        const int k = (i / NCLS) % NCLS;
        const int t = (i / (NCLS * NCLS)) % 2;
        const int n = i / (2 * NCLS * NCLS);
        const float cnt = sums[((n * 2 + 0) * ROWP + NCLS) * COLP + k];
        const float val = sums[((n * 2 + t) * ROWP + c) * COLP + k];
        v[n][t][k][c] = val * (1.f / (cnt + EPSM));
    }
    __syncthreads();

    float acc = 0.f;
    const int NPAIR = NCLS * (NCLS - 1) / 2;   // 171
    for (int i = tid; i < NB * NPAIR; i += 256) {
        const int n = i / NPAIR;
        int rem = i % NPAIR;
        int k1 = 0;
        while (rem >= NCLS - 1 - k1) { rem -= NCLS - 1 - k1; ++k1; }
        const int k2 = k1 + 1 + rem;
        float ss = 0.f, st = 0.f;
#pragma unroll
        for (int c = 0; c < NCLS; ++c) {
            const float ds = v[n][0][k1][c] - v[n][0][k2][c] + EPSPD;
            const float dt = v[n][1][k1][c] - v[n][1][k2][c] + EPSPD;
            ss = fmaf(ds, ds, ss);
            st = fmaf(dt, dt, st);
        }
        const float e = sqrtf(st) - sqrtf(ss);
        acc += 0.5f * e * e;
    }

    red2[tid] = acc;
    __syncthreads();
    for (int s = 128; s > 0; s >>= 1) {
        if (tid < s) red2[tid] += red2[tid + s];
        __syncthreads();
    }
    if (tid == 0) out[0] = 0.5f * red2[0] / (float)NB;
}

extern "C" void kernel_launch(void* const* d_in, const int* in_sizes, int n_in,
                              void* d_out, int out_size, void* d_ws, size_t ws_size,
                              hipStream_t stream) {
    const float* S  = (const float*)d_in[0];
    const float* T  = (const float*)d_in[1];
    const int*   gt = (const int*)d_in[2];

    float* sums = (float*)d_ws;
    hipMemsetAsync(d_ws, 0, SUMS_ELEMS * sizeof(float), stream);

    dim3 grid(HWSZ / CHUNK, NB);   // (256, 8) = 2048 blocks
    icl_sums<<<grid, 256, 0, stream>>>(S, T, gt, sums);
    icl_final<<<1, 256, 0, stream>>>(sums, (float*)d_out);
}

// Round 4
// 157.364 us; speedup vs baseline: 2.0263x; 2.0263x over previous
//
#include <hip/hip_runtime.h>

#define NCLS 19
#define HWSZ (512*1024)
#define NB   8
#define CHUNK 2048            // pixels per block
#define TPX   256             // pixels per staged tile
#define NT    (CHUNK/TPX)     // 8 tiles per chunk
#define EPSM  1e-6f
#define EPSPD 1e-6f

// ws: sums[n][t][row 0..19][col 0..31] f32; row=channel (t=0 row19 = counts), col=class
#define ROWP 20
#define COLP 32
#define SUMS_ELEMS (NB*2*ROWP*COLP)
#define F4T  (NCLS*TPX/4)     // 1216 float4 granules per tensor-tile

typedef short bf16x8 __attribute__((ext_vector_type(8)));
typedef float f32x16 __attribute__((ext_vector_type(16)));

__device__ __forceinline__ short bfh(float v) {
    return (short)(__builtin_bit_cast(unsigned, v) >> 16);
}
__device__ __forceinline__ short bfl(float v) {
    unsigned u = __builtin_bit_cast(unsigned, v);
    float lf = v - __builtin_bit_cast(float, u & 0xFFFF0000u);
    return (short)(__builtin_bit_cast(unsigned, lf) >> 16);
}

// ---- staging in NAMED registers (no arrays, no lambdas -> no scratch) ----
#define STAGE_DECL(j) float4 sreg##j, treg##j; long off##j; int lds##j;

#define STAGE_INIT(j) {                                                     \
    int f = tid + (j) * 256; if ((j) == 4 && f >= F4T) f = F4T - 1;         \
    const int row_ = f >> 6, g_ = f & 63;                                   \
    off##j = ((long)(n * NCLS + row_)) * HWSZ + chunk0 + g_ * 4;            \
    lds##j = row_ * 64 + (g_ ^ (row_ & 7)); }

#define STAGE_LOAD(j, tt) {                                                 \
    const long o_ = off##j + (long)(tt) * TPX;                              \
    sreg##j = *(const float4*)(S + o_);                                     \
    treg##j = *(const float4*)(T + o_); }

#define STAGE_WRITE(j)                                                      \
    if ((j) < 4 || tid + (j) * 256 < F4T) {                                 \
        ((float4*)Sb)[lds##j] = sreg##j;                                    \
        ((float4*)Tb)[lds##j] = treg##j; }

__global__ __launch_bounds__(256, 3) void icl_sums(
    const float* __restrict__ S, const float* __restrict__ T,
    const int* __restrict__ gt, float* __restrict__ sums)
{
    __shared__ float Sb[NCLS * TPX];          // XOR-swizzled 16B granules
    __shared__ float Tb[NCLS * TPX];
    __shared__ int   lab[CHUNK];
    __shared__ float red[2][ROWP][COLP];      // zero during compute: zero-source for r>=19

    const int tid = threadIdx.x;
    const int n   = blockIdx.y;
    const long chunk0 = (long)blockIdx.x * CHUNK;

    for (int i = tid; i < 2 * ROWP * COLP; i += 256) ((float*)red)[i] = 0.f;

    // labels: coalesced load -> LDS immediately (visible after first loop barrier)
    const int4* gp = (const int4*)(gt + (long)n * HWSZ + chunk0);
    ((int4*)lab)[tid]       = gp[tid];
    ((int4*)lab)[tid + 256] = gp[tid + 256];

    const int wave = tid >> 6;
    const int lane = tid & 63;
    const int r    = lane & 31;     // A-row (channel) / B-col (class)
    const int kg   = lane >> 5;     // 8-pixel half of the 16-pixel K-step
    const bool isT = wave >= 2;     // waves 0,1 -> S ; 2,3 -> T
    const int  ph  = wave & 1;      // pixel half of the 256-px tile

    STAGE_DECL(0) STAGE_DECL(1) STAGE_DECL(2) STAGE_DECL(3) STAGE_DECL(4)
    STAGE_INIT(0) STAGE_INIT(1) STAGE_INIT(2) STAGE_INIT(3) STAGE_INIT(4)

    f32x16 acc = {0,0,0,0,0,0,0,0,0,0,0,0,0,0,0,0};
    const bf16x8 ones = {0x3F80,0x3F80,0x3F80,0x3F80,0x3F80,0x3F80,0x3F80,0x3F80};

    const float* xb = isT ? Tb : Sb;
    const float* zb = (const float*)red;      // all-zero source for r >= NCLS

    STAGE_LOAD(0, 0) STAGE_LOAD(1, 0) STAGE_LOAD(2, 0) STAGE_LOAD(3, 0) STAGE_LOAD(4, 0)

    for (int t = 0; t < NT; ++t) {
        if (t > 0) __syncthreads();            // compute on tile t-1 done reading LDS
        STAGE_WRITE(0) STAGE_WRITE(1) STAGE_WRITE(2) STAGE_WRITE(3) STAGE_WRITE(4)
        __syncthreads();
        if (t + 1 < NT) {
            STAGE_LOAD(0, t + 1) STAGE_LOAD(1, t + 1) STAGE_LOAD(2, t + 1)
            STAGE_LOAD(3, t + 1) STAGE_LOAD(4, t + 1)
        }

#pragma unroll
        for (int st = 0; st < 8; ++st) {
            const int px = ph * 128 + st * 16 + kg * 8;   // within tile

            // B fragment: one-hot of labels (exact in bf16)
            const int4 l0 = *(const int4*)&lab[t * TPX + px];
            const int4 l1 = *(const int4*)&lab[t * TPX + px + 4];
            bf16x8 B;
            B[0] = (l0.x == r) ? (short)0x3F80 : (short)0;
            B[1] = (l0.y == r) ? (short)0x3F80 : (short)0;
            B[2] = (l0.z == r) ? (short)0x3F80 : (short)0;
            B[3] = (l0.w == r) ? (short)0x3F80 : (short)0;
            B[4] = (l1.x == r) ? (short)0x3F80 : (short)0;
            B[5] = (l1.y == r) ? (short)0x3F80 : (short)0;
            B[6] = (l1.z == r) ? (short)0x3F80 : (short)0;
            B[7] = (l1.w == r) ? (short)0x3F80 : (short)0;

            // A fragment from LDS (swizzled); lanes r>=19 read zeros from red[]
            const int go  = px >> 2;
            const int gr0 = go ^ (r & 7);
            const int gr1 = (go + 1) ^ (r & 7);
            const float4* f4 = (const float4*)((r < NCLS) ? (xb + r * TPX) : zb);
            const float4 d0 = f4[gr0];
            const float4 d1 = f4[gr1];

            bf16x8 hi, lo;
            hi[0]=bfh(d0.x); lo[0]=bfl(d0.x);  hi[1]=bfh(d0.y); lo[1]=bfl(d0.y);
            hi[2]=bfh(d0.z); lo[2]=bfl(d0.z);  hi[3]=bfh(d0.w); lo[3]=bfl(d0.w);
            hi[4]=bfh(d1.x); lo[4]=bfl(d1.x);  hi[5]=bfh(d1.y); lo[5]=bfl(d1.y);
            hi[6]=bfh(d1.z); lo[6]=bfl(d1.z);  hi[7]=bfh(d1.w); lo[7]=bfl(d1.w);

            if (r == NCLS && !isT) hi = ones;  // count row (S-waves only); lo stays 0

            acc = __builtin_amdgcn_mfma_f32_32x32x16_bf16(hi, B, acc, 0, 0, 0);
            acc = __builtin_amdgcn_mfma_f32_32x32x16_bf16(lo, B, acc, 0, 0, 0);
        }
    }

    // C/D layout: col = lane&31, row = (e&3) + 8*(e>>2) + 4*(lane>>5)
#pragma unroll
    for (int e = 0; e < 16; ++e) {
        const int row = (e & 3) + 8 * (e >> 2) + 4 * kg;
        if (row < ROWP) atomicAdd(&red[isT ? 1 : 0][row][r], acc[e]);
    }
    __syncthreads();

    float* gs = sums + (long)n * 2 * ROWP * COLP;
    for (int i = tid; i < 2 * ROWP * COLP; i += 256) {
        if ((i & 31) < NCLS) atomicAdd(&gs[i], ((const float*)red)[i]);
    }
}

__global__ __launch_bounds__(256) void icl_final(
    const float* __restrict__ sums, float* __restrict__ out)
{
    __shared__ float v[NB][2][NCLS][NCLS];   // [n][t][k][c]
    __shared__ float red2[256];
    const int tid = threadIdx.x;

    for (int i = tid; i < NB * 2 * NCLS * NCLS; i += 256) {
        const int c = i % NCLS;
        const int k = (i / NCLS) % NCLS;
        const int t = (i / (NCLS * NCLS)) % 2;
        const int n = i / (2 * NCLS * NCLS);
        const float cnt = sums[((n * 2 + 0) * ROWP + NCLS) * COLP + k];
        const float val = sums[((n * 2 + t) * ROWP + c) * COLP + k];
        v[n][t][k][c] = val * (1.f / (cnt + EPSM));
    }
    __syncthreads();

    float acc = 0.f;
    const int NPAIR = NCLS * (NCLS - 1) / 2;   // 171
    for (int i = tid; i < NB * NPAIR; i += 256) {
        const int n = i / NPAIR;
        int rem = i % NPAIR;
        int k1 = 0;
        while (rem >= NCLS - 1 - k1) { rem -= NCLS - 1 - k1; ++k1; }
        const int k2 = k1 + 1 + rem;
        float ss = 0.f, st = 0.f;
#pragma unroll
        for (int c = 0; c < NCLS; ++c) {
            const float ds = v[n][0][k1][c] - v[n][0][k2][c] + EPSPD;
            const float dt = v[n][1][k1][c] - v[n][1][k2][c] + EPSPD;
            ss = fmaf(ds, ds, ss);
            st = fmaf(dt, dt, st);
        }
        const float e = sqrtf(st) - sqrtf(ss);
        acc += 0.5f * e * e;
    }

    red2[tid] = acc;
    __syncthreads();
    for (int s = 128; s > 0; s >>= 1) {
        if (tid < s) red2[tid] += red2[tid + s];
        __syncthreads();
    }
    if (tid == 0) out[0] = 0.5f * red2[0] / (float)NB;
}

extern "C" void kernel_launch(void* const* d_in, const int* in_sizes, int n_in,
                              void* d_out, int out_size, void* d_ws, size_t ws_size,
                              hipStream_t stream) {
    const float* S  = (const float*)d_in[0];
    const float* T  = (const float*)d_in[1];
    const int*   gt = (const int*)d_in[2];

    float* sums = (float*)d_ws;
    hipMemsetAsync(d_ws, 0, SUMS_ELEMS * sizeof(float), stream);

    dim3 grid(HWSZ / CHUNK, NB);   // (256, 8) = 2048 blocks
    icl_sums<<<grid, 256, 0, stream>>>(S, T, gt, sums);
    icl_final<<<1, 256, 0, stream>>>(sums, (float*)d_out);
}

// Round 5
// 152.200 us; speedup vs baseline: 2.0951x; 1.0339x over previous
//
#include <hip/hip_runtime.h>

#define NCLS 19
#define HWSZ (512*1024)
#define NB   8
#define CHUNK 2048            // pixels per block
#define TPX   256             // pixels per staged tile
#define NT    (CHUNK/TPX)     // 8 tiles
#define EPSM  1e-6f
#define EPSPD 1e-6f

#define ROWP 20
#define COLP 32
#define SUMS_ELEMS (NB*2*ROWP*COLP)
#define F4T  (NCLS*TPX/4)     // 1216 float4 granules per tensor-tile

typedef short bf16x8 __attribute__((ext_vector_type(8)));
typedef float f32x16 __attribute__((ext_vector_type(16)));
typedef unsigned uint4v __attribute__((ext_vector_type(4)));

// ---------- staging in NAMED registers, 2 sets (depth-2 prefetch) ----------
#define SG_DECL(set) float4 s##set##0, s##set##1, s##set##2, s##set##3, s##set##4, \
                            t##set##0, t##set##1, t##set##2, t##set##3, t##set##4;

#define SG_INIT(j) { int f = tid + (j)*256; if ((j) == 4 && f >= F4T) f = F4T - 1; \
    const int row_ = f >> 6, g_ = f & 63;                                          \
    const int blk_ = ((g_ >> 2) << 1) | (g_ & 1);          /* st*2 + h  */         \
    const int slot_ = (((g_ >> 1) & 1) * 20) + row_;       /* kg*20+row */         \
    widx##j = blk_ * 40 + (slot_ ^ (blk_ & 7));                                     \
    goff##j = ((long)(n * NCLS + row_)) * HWSZ + chunk0 + (g_ << 2); }

#define SG_LOAD(set, j, tt) { const long o_ = goff##j + (long)(tt) * TPX; \
    s##set##j = *(const float4*)(S + o_);                                 \
    t##set##j = *(const float4*)(T + o_); }

#define SG_LOADS(set, tt) SG_LOAD(set,0,tt) SG_LOAD(set,1,tt) SG_LOAD(set,2,tt) \
                          SG_LOAD(set,3,tt) SG_LOAD(set,4,tt)

#define SG_WRITE(set, j) { Sb4[widx##j] = s##set##j; Tb4[widx##j] = t##set##j; }
#define SG_WRITES(set) SG_WRITE(set,0) SG_WRITE(set,1) SG_WRITE(set,2) \
                       SG_WRITE(set,3) SG_WRITE(set,4)

// fp32 -> packed bf16 hi / lo (exact split; hi = truncation, lo = remainder)
#define CVT(pA, pB, HI, LO) {                                                      \
    const unsigned uA = __builtin_bit_cast(unsigned, pA);                          \
    const unsigned uB = __builtin_bit_cast(unsigned, pB);                          \
    HI = __builtin_amdgcn_perm(uB, uA, 0x07060302u);                               \
    const float fa = (pA) - __builtin_bit_cast(float, uA & 0xFFFF0000u);           \
    const float fb = (pB) - __builtin_bit_cast(float, uB & 0xFFFF0000u);           \
    LO = __builtin_amdgcn_perm(__builtin_bit_cast(unsigned, fb),                   \
                               __builtin_bit_cast(unsigned, fa), 0x07060302u); }

#define BBIT(word, sh, ei) { const unsigned lb_ = ((word) >> (sh)) & 255u;         \
    B[ei] = (lb_ == ur) ? (short)0x3F80 : (short)0; }

#define COMPUTE_TILE(t_) {                                                          \
    _Pragma("unroll")                                                               \
    for (int i = 0; i < 8; ++i) {                                                   \
        const uint2 pk = *(const uint2*)(labP + (t_) * 256 + i * 16);               \
        const float4 d0 = xb4[ra[(2*i) & 7]     + (2*i) * 40];                      \
        const float4 d1 = xb4[ra[(2*i+1) & 7]   + (2*i+1) * 40];                    \
        bf16x8 B;                                                                   \
        BBIT(pk.x, 0, 0) BBIT(pk.x, 8, 1) BBIT(pk.x, 16, 2) BBIT(pk.x, 24, 3)      \
        BBIT(pk.y, 0, 4) BBIT(pk.y, 8, 5) BBIT(pk.y, 16, 6) BBIT(pk.y, 24, 7)      \
        unsigned h0, h1, h2, h3, l0_, l1_, l2_, l3_;                                \
        CVT(d0.x, d0.y, h0, l0_)  CVT(d0.z, d0.w, h1, l1_)                          \
        CVT(d1.x, d1.y, h2, l2_)  CVT(d1.z, d1.w, h3, l3_)                          \
        const bf16x8 hi = __builtin_bit_cast(bf16x8, (uint4v){h0, h1, h2, h3});     \
        const bf16x8 lo = __builtin_bit_cast(bf16x8, (uint4v){l0_, l1_, l2_, l3_}); \
        acc = __builtin_amdgcn_mfma_f32_32x32x16_bf16(hi, B, acc, 0, 0, 0);         \
        acc = __builtin_amdgcn_mfma_f32_32x32x16_bf16(lo, B, acc, 0, 0, 0);         \
    } }

#define TILE(set, t_) {                                                             \
    if ((t_) > 0) __syncthreads();                                                  \
    SG_WRITES(set)                                                                  \
    __syncthreads();                                                                \
    if ((t_) + 2 < NT) { SG_LOADS(set, (t_) + 2) }                                  \
    COMPUTE_TILE(t_) }

__global__ __launch_bounds__(256, 3) void icl_sums(
    const float* __restrict__ S, const float* __restrict__ T,
    const int* __restrict__ gt, float* __restrict__ sums)
{
    __shared__ float4 Sb4[32 * 40];            // [block 0..31][slot 0..39], swizzled
    __shared__ float4 Tb4[32 * 40];
    __shared__ unsigned char labU[CHUNK];      // labels as bytes
    __shared__ float red[2][ROWP][COLP];

    const int tid = threadIdx.x;
    const int n   = blockIdx.y;
    const long chunk0 = (long)blockIdx.x * CHUNK;

    for (int i = tid; i < 2 * ROWP * COLP; i += 256) ((float*)red)[i] = 0.f;

    // prefill count row (slot kg*20+19) with 1.0f in every block, both buffers;
    // stagers only ever write rows 0..18, so this persists across tiles.
    if (tid < 128) {
        const int b = tid >> 2, kg_ = (tid >> 1) & 1, tb = tid & 1;
        const int idx = b * 40 + (((kg_ * 20) + 19) ^ (b & 7));
        (tb ? Tb4 : Sb4)[idx] = make_float4(1.f, 1.f, 1.f, 1.f);
    }

    // labels -> packed u8 in LDS (coalesced)
    {
        const int4* gp = (const int4*)(gt + (long)n * HWSZ + chunk0);
        const int4 a = gp[tid], b = gp[tid + 256];
        const unsigned p0 = (unsigned)a.x | ((unsigned)a.y << 8) |
                            ((unsigned)a.z << 16) | ((unsigned)a.w << 24);
        const unsigned p1 = (unsigned)b.x | ((unsigned)b.y << 8) |
                            ((unsigned)b.z << 16) | ((unsigned)b.w << 24);
        ((unsigned*)labU)[tid]       = p0;
        ((unsigned*)labU)[tid + 256] = p1;
    }

    int widx0, widx1, widx2, widx3, widx4;
    long goff0, goff1, goff2, goff3, goff4;
    SG_INIT(0) SG_INIT(1) SG_INIT(2) SG_INIT(3) SG_INIT(4)
    SG_DECL(A) SG_DECL(B)

    const int wave = tid >> 6, lane = tid & 63;
    const int r  = lane & 31;                   // A-row (channel) / B-col (class)
    const int kg = lane >> 5;                   // 8-px half of the 16-px K-step
    const bool isT = wave >= 2;
    const int  ph  = wave & 1;                  // 128-px half of the tile
    const unsigned ur = (unsigned)r;

    // A-read element indices: idx = ph*640 + (2i+h)*40 + (sbase ^ ((2i+h)&7))
    const int sbase = kg * 20 + (r < 20 ? r : r - 12);   // r>=20: harmless dup rows
    int ra[8];
#pragma unroll
    for (int k = 0; k < 8; ++k) ra[k] = ph * 640 + (sbase ^ k);

    const float4* xb4 = isT ? Tb4 : Sb4;
    const unsigned char* labP = labU + ph * 128 + kg * 8;

    f32x16 acc = {0,0,0,0,0,0,0,0,0,0,0,0,0,0,0,0};

    SG_LOADS(A, 0)
    SG_LOADS(B, 1)

    TILE(A, 0) TILE(B, 1) TILE(A, 2) TILE(B, 3)
    TILE(A, 4) TILE(B, 5) TILE(A, 6) TILE(B, 7)

    // C/D layout: col = lane&31, row = (e&3) + 8*(e>>2) + 4*(lane>>5)
#pragma unroll
    for (int e = 0; e < 16; ++e) {
        const int row = (e & 3) + 8 * (e >> 2) + 4 * kg;
        if (row < ROWP) atomicAdd(&red[isT ? 1 : 0][row][r], acc[e]);
    }
    __syncthreads();

    float* gs = sums + (long)n * 2 * ROWP * COLP;
    for (int i = tid; i < 2 * ROWP * COLP; i += 256) {
        if ((i & 31) < NCLS) atomicAdd(&gs[i], ((const float*)red)[i]);
    }
}

__global__ __launch_bounds__(256) void icl_final(
    const float* __restrict__ sums, float* __restrict__ out)
{
    __shared__ float v[NB][2][NCLS][NCLS];   // [n][t][k][c]
    __shared__ float red2[256];
    const int tid = threadIdx.x;

    for (int i = tid; i < NB * 2 * NCLS * NCLS; i += 256) {
        const int c = i % NCLS;
        const int k = (i / NCLS) % NCLS;
        const int t = (i / (NCLS * NCLS)) % 2;
        const int n = i / (2 * NCLS * NCLS);
        const float cnt = sums[((n * 2 + 0) * ROWP + NCLS) * COLP + k];
        const float val = sums[((n * 2 + t) * ROWP + c) * COLP + k];
        v[n][t][k][c] = val * (1.f / (cnt + EPSM));
    }
    __syncthreads();

    float acc = 0.f;
    const int NPAIR = NCLS * (NCLS - 1) / 2;   // 171
    for (int i = tid; i < NB * NPAIR; i += 256) {
        const int n = i / NPAIR;
        int rem = i % NPAIR;
        int k1 = 0;
        while (rem >= NCLS - 1 - k1) { rem -= NCLS - 1 - k1; ++k1; }
        const int k2 = k1 + 1 + rem;
        float ss = 0.f, st = 0.f;
#pragma unroll
        for (int c = 0; c < NCLS; ++c) {
            const float ds = v[n][0][k1][c] - v[n][0][k2][c] + EPSPD;
            const float dt = v[n][1][k1][c] - v[n][1][k2][c] + EPSPD;
            ss = fmaf(ds, ds, ss);
            st = fmaf(dt, dt, st);
        }
        const float e = sqrtf(st) - sqrtf(ss);
        acc += 0.5f * e * e;
    }

    red2[tid] = acc;
    __syncthreads();
    for (int s = 128; s > 0; s >>= 1) {
        if (tid < s) red2[tid] += red2[tid + s];
        __syncthreads();
    }
    if (tid == 0) out[0] = 0.5f * red2[0] / (float)NB;
}

extern "C" void kernel_launch(void* const* d_in, const int* in_sizes, int n_in,
                              void* d_out, int out_size, void* d_ws, size_t ws_size,
                              hipStream_t stream) {
    const float* S  = (const float*)d_in[0];
    const float* T  = (const float*)d_in[1];
    const int*   gt = (const int*)d_in[2];

    float* sums = (float*)d_ws;
    hipMemsetAsync(d_ws, 0, SUMS_ELEMS * sizeof(float), stream);

    dim3 grid(HWSZ / CHUNK, NB);   // (256, 8) = 2048 blocks
    icl_sums<<<grid, 256, 0, stream>>>(S, T, gt, sums);
    icl_final<<<1, 256, 0, stream>>>(sums, (float*)d_out);
}